// Round 1
// baseline (198.093 us; speedup 1.0000x reference)
//
#include <hip/hip_runtime.h>

#define BATCH 128
#define NC1 1152
#define ND1 8
#define NC2 10
#define ND2 16

// One block per batch element. 1024 threads = 64 groups of 16 lanes.
// Group g handles capsules c = g, g+64, ... (18 each). Lane within group = d (D2 index).
__global__ __launch_bounds__(1024) void caps_routing(
    const float* __restrict__ x,     // [B, C1*D1]
    const float* __restrict__ W,     // [C1, C2, D2, D1]
    const float* __restrict__ bias,  // [C2*D2]
    float* __restrict__ out)         // [B, C2*D2]
{
    const int b    = blockIdx.x;
    const int tid  = threadIdx.x;
    const int grp  = tid >> 4;   // 0..63
    const int d    = tid & 15;   // D2 lane
    const int wave = tid >> 6;   // 0..15
    const int lane = tid & 63;

    __shared__ float prim[NC1][ND1];       // 36 KB: squashed primary caps
    __shared__ float sred[16][NC2 * ND2];  // 10 KB: per-wave s partials
    __shared__ float vbuf[NC2 * ND2];      // 640 B: broadcast v

    const float* xb = x + (size_t)b * (NC1 * ND1);

    // ---- PrimaryCaps squash: prim[c] = x[c] * (sq/(1+sq))/sqrt(sq+eps) ----
    for (int c = tid; c < NC1; c += 1024) {
        float4 a0 = *(const float4*)(xb + c * 8);
        float4 a1 = *(const float4*)(xb + c * 8 + 4);
        float sq = a0.x*a0.x + a0.y*a0.y + a0.z*a0.z + a0.w*a0.w
                 + a1.x*a1.x + a1.y*a1.y + a1.z*a1.z + a1.w*a1.w;
        float g = (sq / (1.0f + sq)) * rsqrtf(sq + 1e-8f);
        prim[c][0] = a0.x * g; prim[c][1] = a0.y * g;
        prim[c][2] = a0.z * g; prim[c][3] = a0.w * g;
        prim[c][4] = a1.x * g; prim[c][5] = a1.y * g;
        prim[c][6] = a1.z * g; prim[c][7] = a1.w * g;
    }
    __syncthreads();

    float vsum[NC2];  // running v0 (pass1), v0+v1 (pass2) at this lane's d
    float sp[NC2];    // per-lane partial s[j] (d implicit in lane)

    for (int pass = 0; pass < 3; ++pass) {
        #pragma unroll
        for (int j = 0; j < NC2; ++j) sp[j] = 0.0f;

        for (int c = grp; c < NC1; c += 64) {
            float p[8];
            #pragma unroll
            for (int k = 0; k < 8; ++k) p[k] = prim[c][k];

            const float* Wc = W + (size_t)c * (NC2 * ND2 * ND1) + d * ND1;
            float u[NC2];
            #pragma unroll
            for (int j = 0; j < NC2; ++j) {
                const float4 w0 = *(const float4*)(Wc + j * (ND2 * ND1));
                const float4 w1 = *(const float4*)(Wc + j * (ND2 * ND1) + 4);
                u[j] = w0.x*p[0] + w0.y*p[1] + w0.z*p[2] + w0.w*p[3]
                     + w1.x*p[4] + w1.y*p[5] + w1.z*p[6] + w1.w*p[7];
            }

            if (pass == 0) {
                // softmax(0) = uniform 1/10 -> fold 0.1 into the final reduce
                #pragma unroll
                for (int j = 0; j < NC2; ++j) sp[j] += u[j];
            } else {
                // raw[c,j] = dot_d(u, v0)  (pass1)  or  dot_d(u, v0+v1)  (pass2)
                float r[NC2];
                #pragma unroll
                for (int j = 0; j < NC2; ++j) {
                    float t = u[j] * vsum[j];
                    t += __shfl_xor(t, 1);
                    t += __shfl_xor(t, 2);
                    t += __shfl_xor(t, 4);
                    t += __shfl_xor(t, 8);
                    r[j] = t;
                }
                // softmax over j (all 16 lanes hold identical r[] -> uniform)
                float m = r[0];
                #pragma unroll
                for (int j = 1; j < NC2; ++j) m = fmaxf(m, r[j]);
                float ssum = 0.0f;
                #pragma unroll
                for (int j = 0; j < NC2; ++j) { r[j] = __expf(r[j] - m); ssum += r[j]; }
                float inv = 1.0f / ssum;
                #pragma unroll
                for (int j = 0; j < NC2; ++j) sp[j] += (r[j] * inv) * u[j];
            }
        }

        // ---- reduce s over the 64 groups: intra-wave shfl, then LDS over waves ----
        #pragma unroll
        for (int j = 0; j < NC2; ++j) {
            sp[j] += __shfl_xor(sp[j], 16);
            sp[j] += __shfl_xor(sp[j], 32);
        }
        if (lane < 16) {
            #pragma unroll
            for (int j = 0; j < NC2; ++j) sred[wave][j * 16 + d] = sp[j];
        }
        __syncthreads();

        // ---- final s, bias, squash -> v (threads 0..159: j = tid/16, dd = tid%16) ----
        if (tid < NC2 * ND2) {
            float acc = 0.0f;
            #pragma unroll
            for (int w = 0; w < 16; ++w) acc += sred[w][tid];
            float s = bias[tid] + (pass == 0 ? 0.1f * acc : acc);
            float sq = s * s;
            sq += __shfl_xor(sq, 1);
            sq += __shfl_xor(sq, 2);
            sq += __shfl_xor(sq, 4);
            sq += __shfl_xor(sq, 8);
            float vv = (sq / (1.0f + sq)) * rsqrtf(sq + 1e-8f) * s;
            if (pass == 2) out[(size_t)b * (NC2 * ND2) + tid] = vv;
            else           vbuf[tid] = vv;
        }
        __syncthreads();

        if (pass < 2) {
            #pragma unroll
            for (int j = 0; j < NC2; ++j) {
                float vv = vbuf[j * 16 + d];
                vsum[j] = (pass == 0) ? vv : (vsum[j] + vv);
            }
        }
        // no barrier needed here: next pass's sred/vbuf writes are separated
        // from this pass's reads by the __syncthreads() above / compute loop
    }
}

extern "C" void kernel_launch(void* const* d_in, const int* in_sizes, int n_in,
                              void* d_out, int out_size, void* d_ws, size_t ws_size,
                              hipStream_t stream) {
    const float* x    = (const float*)d_in[0];  // [128, 9216]
    const float* W    = (const float*)d_in[1];  // [1152, 10, 16, 8]
    const float* bias = (const float*)d_in[2];  // [1, 1, 10, 16]
    float* out = (float*)d_out;                 // [128, 1, 10, 16, 1]

    caps_routing<<<BATCH, 1024, 0, stream>>>(x, W, bias, out);
}